// Round 2
// baseline (522.209 us; speedup 1.0000x reference)
//
#include <hip/hip_runtime.h>
#include <stdint.h>

#define TSEQ   2048
#define NBATCH 8
#define NHEAD  4
#define HD     100
#define EMBED  400
#define KP     416      // EMBED padded to multiple of 32
#define QLD    1536     // per-token QKV row: 4 heads * 3 mats * 128 (headdim padded)
#define DFF    1600
#define NROWS  (NBATCH*TSEQ)   // 16384

#define FLAG_RELU    1
#define FLAG_BF16OUT 2

typedef __attribute__((ext_vector_type(4))) float f32x4;
typedef __attribute__((ext_vector_type(8))) short s16x8;
typedef __attribute__((ext_vector_type(4))) unsigned short u16x4;
typedef unsigned short u16;

__device__ __forceinline__ u16 f2bf(float f) {
  union { float f; unsigned u; } v; v.f = f;
  unsigned r = v.u + 0x7FFFu + ((v.u >> 16) & 1u);   // RNE
  return (u16)(r >> 16);
}

__device__ __forceinline__ void gld16(const u16* g, u16* l) {
  __builtin_amdgcn_global_load_lds(
      (const __attribute__((address_space(1))) unsigned*)g,
      (__attribute__((address_space(3))) unsigned*)l, 16, 0, 0);
}

// ---------------- weight repack: fp32 -> bf16, B^T [N][K] layouts ----------
__global__ __launch_bounds__(256) void repack_kernel(
    const float* __restrict__ Wq, const float* __restrict__ Wk, const float* __restrict__ Wv,
    const float* __restrict__ Wo, const float* __restrict__ W1, const float* __restrict__ W2,
    u16* __restrict__ wqkv, u16* __restrict__ wo, u16* __restrict__ w1, u16* __restrict__ w2)
{
  int i = blockIdx.x * 256 + threadIdx.x;
  const int n1 = 1536*KP, n2 = 512*KP, n3 = 1664*KP, n4 = 512*DFF;
  if (i < n1) {            // qkv: n = h*384 + w*128 + d  (w: 0=Q,1=K,2=V)
    int n = i / KP, k = i - n*KP;
    int hh = n / 384, rem = n - hh*384;
    int w = rem >> 7, d = rem & 127;
    float v = 0.f;
    if (k < EMBED && d < HD) {
      const float* W = (w == 0) ? Wq : (w == 1) ? Wk : Wv;
      v = W[(hh*EMBED + k)*HD + d];
    }
    wqkv[i] = f2bf(v);
    return;
  }
  i -= n1;
  if (i < n2) {
    int n = i / KP, k = i - n*KP;
    float v = (n < EMBED && k < EMBED) ? Wo[k*EMBED + n] : 0.f;
    wo[i] = f2bf(v);
    return;
  }
  i -= n2;
  if (i < n3) {
    int n = i / KP, k = i - n*KP;
    float v = (n < DFF && k < EMBED) ? W1[k*DFF + n] : 0.f;
    w1[i] = f2bf(v);
    return;
  }
  i -= n3;
  if (i < n4) {
    int n = i / DFF, k = i - n*DFF;
    float v = (n < EMBED) ? W2[k*EMBED + n] : 0.f;
    w2[i] = f2bf(v);
  }
}

// ---------------- layernorm: fp32 in -> bf16 out [row][KP], pads zeroed ----
__global__ __launch_bounds__(256) void ln_kernel(
    const float* __restrict__ x, const float* __restrict__ gam, const float* __restrict__ bet,
    u16* __restrict__ out)
{
  int wave = threadIdx.x >> 6, lane = threadIdx.x & 63;
  int row = blockIdx.x * 4 + wave;
  const float* xr = x + row*EMBED;
  float v[7]; float s = 0.f;
  #pragma unroll
  for (int j=0;j<7;++j) { int idx = lane + j*64; v[j] = (idx < EMBED) ? xr[idx] : 0.f; s += v[j]; }
  #pragma unroll
  for (int off=1; off<64; off<<=1) s += __shfl_xor(s, off, 64);
  float mu = s * (1.f/EMBED);
  float q = 0.f;
  #pragma unroll
  for (int j=0;j<7;++j) { int idx = lane + j*64; if (idx < EMBED) { float d = v[j]-mu; q += d*d; } }
  #pragma unroll
  for (int off=1; off<64; off<<=1) q += __shfl_xor(q, off, 64);
  float rstd = rsqrtf(q * (1.f/EMBED) + 1e-5f);
  u16* orow = out + row*KP;
  #pragma unroll
  for (int j=0;j<7;++j) {
    int idx = lane + j*64;
    if (idx < KP) {
      float o = (idx < EMBED) ? (v[j]-mu)*rstd*gam[idx] + bet[idx] : 0.f;
      orow[idx] = f2bf(o);
    }
  }
}

// ---------------- generic bf16 GEMM: C = A[M][K] * Bt[N][K]^T + epilogue ----
// 128x128 tile, BK=32, 4 waves (2x2), global_load_lds staging (m97 structure)
__global__ __launch_bounds__(256) void gemm_bf16(
    const u16* __restrict__ A, int lda,
    const u16* __restrict__ Bt, int ldb,
    void* __restrict__ Cout, int ldc,
    const float* __restrict__ bias,
    const float* __restrict__ resid, int ldres,
    int N, int ksteps, int flags)
{
  __shared__ u16 As[128*32];
  __shared__ u16 Bs[128*32];
  const int tid  = threadIdx.x;
  const int lane = tid & 63, wave = tid >> 6;
  const int wm = wave >> 1, wn = wave & 1;
  const int r15 = lane & 15, g = lane >> 4;
  const int brow = blockIdx.x * 128;
  const int bcol = blockIdx.y * 128;

  f32x4 acc[4][4] = {};
  const int c0 = wave*128 + lane;   // this thread's first 16B staging chunk

  for (int ks = 0; ks < ksteps; ++ks) {
    #pragma unroll
    for (int i=0;i<2;++i) {
      int c = c0 + i*64;            // 0..511; wave-contiguous => legal lds dest
      int r = c >> 2, kc = c & 3;
      gld16(A  + (brow + r)*lda + ks*32 + kc*8, As + c*8);
      gld16(Bt + (bcol + r)*ldb + ks*32 + kc*8, Bs + c*8);
    }
    __syncthreads();
    s16x8 af[4], bq[4];
    #pragma unroll
    for (int mi=0;mi<4;++mi)
      af[mi] = *(const s16x8*)(As + (wm*64 + mi*16 + r15)*32 + g*8);
    #pragma unroll
    for (int ni=0;ni<4;++ni)
      bq[ni] = *(const s16x8*)(Bs + (wn*64 + ni*16 + r15)*32 + g*8);
    #pragma unroll
    for (int mi=0;mi<4;++mi)
      #pragma unroll
      for (int ni=0;ni<4;++ni)
        acc[mi][ni] = __builtin_amdgcn_mfma_f32_16x16x32_bf16(af[mi], bq[ni], acc[mi][ni], 0, 0, 0);
    __syncthreads();
  }

  #pragma unroll
  for (int ni=0;ni<4;++ni) {
    const int col = bcol + wn*64 + ni*16 + r15;
    if (col >= N) continue;
    const float bv = bias ? bias[col] : 0.f;
    #pragma unroll
    for (int mi=0;mi<4;++mi) {
      #pragma unroll
      for (int e=0;e<4;++e) {
        const int row = brow + wm*64 + mi*16 + g*4 + e;
        float v = acc[mi][ni][e] + bv;
        if (flags & FLAG_RELU) v = fmaxf(v, 0.f);
        if (resid) v += resid[row*ldres + col];
        if (flags & FLAG_BF16OUT) ((u16*)Cout)[row*ldc + col] = f2bf(v);
        else                      ((float*)Cout)[row*ldc + col] = v;
      }
    }
  }
}

// ---------------- causal flash attention -----------------------------------
// grid (T/64, B*H), 4 waves; wave w owns q-rows [w*16, w*16+16) of the tile.
#define VS 72   // Vt / Ps padded stride (bank-conflict avoidance)
__global__ __launch_bounds__(256) void attn_kernel(
    const u16* __restrict__ qkv, u16* __restrict__ aout)
{
  const int qi = blockIdx.x;
  const int bh = blockIdx.y;
  const int b = bh >> 2, h = bh & 3;
  const int tid = threadIdx.x;
  const int lane = tid & 63, wave = tid >> 6;
  const int r15 = lane & 15, g = lane >> 4;

  __shared__ u16 Qs[64*128];
  __shared__ u16 Ks[64*128];
  __shared__ u16 Vt[112*VS];        // V transposed: [d][kv]
  __shared__ u16 Ps[4*16*VS];       // per-wave P tile [16][64]

  const int base = (b*TSEQ)*QLD + h*384;

  // stage Q tile (XOR-swizzled source so swizzled reads are conflict-free)
  #pragma unroll
  for (int i=0;i<4;++i) {
    int c = (wave*4 + i)*64 + lane;
    int r = c >> 4, pos = c & 15;
    int dc = pos ^ (r & 7);
    gld16(qkv + base + (qi*64 + r)*QLD + dc*8, Qs + c*8);
  }
  __syncthreads();
  s16x8 qf[4];
  #pragma unroll
  for (int ks=0;ks<4;++ks) {
    int row = wave*16 + r15;
    int pos = (ks*4 + g) ^ (row & 7);
    qf[ks] = *(const s16x8*)(Qs + row*128 + pos*8);
  }

  f32x4 acc_o[7] = {};
  float m_i[4], l_i[4];
  #pragma unroll
  for (int e=0;e<4;++e){ m_i[e] = -1e30f; l_i[e] = 0.f; }

  for (int kj = 0; kj <= qi; ++kj) {
    // stage K tile (async, swizzled)
    #pragma unroll
    for (int i=0;i<4;++i) {
      int c = (wave*4 + i)*64 + lane;
      int r = c >> 4, pos = c & 15;
      int dc = pos ^ (r & 7);
      gld16(qkv + base + 128 + (kj*64 + r)*QLD + dc*8, Ks + c*8);
    }
    // stage V^T (reg->lds scatter; only d<112 needed)
    #pragma unroll
    for (int i=0;i<4;++i) {
      int c = tid + i*256;
      if (c < 896) {
        int kv = c & 63, dc2 = c >> 6;
        s16x8 vv = *(const s16x8*)(qkv + base + 256 + (kj*64 + kv)*QLD + dc2*8);
        #pragma unroll
        for (int e=0;e<8;++e) Vt[(dc2*8+e)*VS + kv] = (u16)vv[e];
      }
    }
    __syncthreads();

    // S = Q K^T  (16 q-rows x 64 kv per wave)
    f32x4 sacc[4] = {};
    #pragma unroll
    for (int ni=0;ni<4;++ni) {
      #pragma unroll
      for (int ks=0;ks<4;++ks) {
        int row = ni*16 + r15;
        int pos = (ks*4 + g) ^ (row & 7);
        s16x8 kf = *(const s16x8*)(Ks + row*128 + pos*8);
        sacc[ni] = __builtin_amdgcn_mfma_f32_16x16x32_bf16(qf[ks], kf, sacc[ni], 0, 0, 0);
      }
    }

    // scale + causal mask + online softmax
    const bool diag = (kj == qi);
    float p[4][4], mx[4];
    #pragma unroll
    for (int e=0;e<4;++e) mx[e] = -1e30f;
    #pragma unroll
    for (int ni=0;ni<4;++ni) {
      int kvo = ni*16 + r15;
      #pragma unroll
      for (int e=0;e<4;++e) {
        float s = sacc[ni][e] * 0.1f;           // 1/sqrt(100)
        if (diag && kvo > wave*16 + g*4 + e) s = -1e30f;
        p[ni][e] = s;
        mx[e] = fmaxf(mx[e], s);
      }
    }
    #pragma unroll
    for (int e=0;e<4;++e) {
      float m = mx[e];
      m = fmaxf(m, __shfl_xor(m, 1, 64));
      m = fmaxf(m, __shfl_xor(m, 2, 64));
      m = fmaxf(m, __shfl_xor(m, 4, 64));
      m = fmaxf(m, __shfl_xor(m, 8, 64));
      mx[e] = m;
    }
    float sc[4];
    #pragma unroll
    for (int e=0;e<4;++e) {
      float mnew = fmaxf(m_i[e], mx[e]);
      sc[e] = __expf(m_i[e] - mnew);
      m_i[e] = mnew;
      float rsum = 0.f;
      #pragma unroll
      for (int ni=0;ni<4;++ni) {
        float pe = __expf(p[ni][e] - mnew);
        p[ni][e] = pe;
        rsum += pe;
      }
      rsum += __shfl_xor(rsum, 1, 64);
      rsum += __shfl_xor(rsum, 2, 64);
      rsum += __shfl_xor(rsum, 4, 64);
      rsum += __shfl_xor(rsum, 8, 64);
      l_i[e] = l_i[e]*sc[e] + rsum;
    }
    #pragma unroll
    for (int ni=0;ni<7;++ni)
      #pragma unroll
      for (int e=0;e<4;++e) acc_o[ni][e] *= sc[e];

    // P (C-frag layout) -> LDS -> A-frag layout (wave-private, no barrier)
    u16* myP = Ps + wave*16*VS;
    #pragma unroll
    for (int ni=0;ni<4;++ni)
      #pragma unroll
      for (int e=0;e<4;++e)
        myP[(g*4+e)*VS + ni*16 + r15] = f2bf(p[ni][e]);
    s16x8 pa[2];
    #pragma unroll
    for (int ks2=0;ks2<2;++ks2)
      pa[ks2] = *(const s16x8*)(myP + r15*VS + ks2*32 + g*8);

    // O += P V
    #pragma unroll
    for (int ni=0;ni<7;++ni) {
      #pragma unroll
      for (int ks2=0;ks2<2;++ks2) {
        s16x8 vf = *(const s16x8*)(Vt + (ni*16 + r15)*VS + ks2*32 + g*8);
        acc_o[ni] = __builtin_amdgcn_mfma_f32_16x16x32_bf16(pa[ks2], vf, acc_o[ni], 0, 0, 0);
      }
    }
    __syncthreads();
  }

  // epilogue: out = acc / l, bf16, concat-head layout [row][KP]
  #pragma unroll
  for (int ni=0;ni<7;++ni) {
    int d = ni*16 + r15;
    if (d < HD) {
      #pragma unroll
      for (int e=0;e<4;++e) {
        int row = b*TSEQ + qi*64 + wave*16 + g*4 + e;
        aout[row*KP + h*HD + d] = f2bf(acc_o[ni][e] / l_i[e]);
      }
    }
  }
  if (h == 0) {  // zero the [400,416) pad columns for the next GEMM
    int r = tid >> 2, c4 = tid & 3;
    int row = b*TSEQ + qi*64 + r;
    *(u16x4*)(aout + row*KP + EMBED + c4*4) = (u16x4){0,0,0,0};
  }
}

// ---------------------------------------------------------------------------
extern "C" void kernel_launch(void* const* d_in, const int* in_sizes, int n_in,
                              void* d_out, int out_size, void* d_ws, size_t ws_size,
                              hipStream_t stream)
{
  const float* x    = (const float*)d_in[0];
  const float* ln1g = (const float*)d_in[1];
  const float* ln1b = (const float*)d_in[2];
  const float* ln2g = (const float*)d_in[3];
  const float* ln2b = (const float*)d_in[4];
  const float* Wq   = (const float*)d_in[5];
  const float* Wk   = (const float*)d_in[6];
  const float* Wv   = (const float*)d_in[7];
  const float* Wo   = (const float*)d_in[8];
  const float* bo   = (const float*)d_in[9];
  const float* W1   = (const float*)d_in[10];
  const float* b1   = (const float*)d_in[11];
  const float* W2   = (const float*)d_in[12];
  const float* b2   = (const float*)d_in[13];

  u16* wsu = (u16*)d_ws;
  u16* wqkv_t = wsu;                  // [1536][416]
  u16* wo_t   = wsu + 638976;         // [512][416]
  u16* w1_t   = wsu + 851968;         // [1664][416]
  u16* w2_t   = wsu + 1544192;        // [512][1600]
  char* wsb = (char*)d_ws;
  u16* h_bf  = (u16*)(wsb + 4726784);   // [16384][416]
  u16* qkv   = (u16*)(wsb + 18358272);  // [16384][1536]
  u16* attn  = (u16*)(wsb + 68689920);  // [16384][416]; reused as h2 after GEMM2
  u16* ff    = h_bf;                    // [16384][1600]; overlays dead h_bf+qkv
  float* x2  = (float*)d_out;           // x+attn residual lives in d_out

  repack_kernel<<<(2363392 + 255)/256, 256, 0, stream>>>(Wq, Wk, Wv, Wo, W1, W2,
                                                         wqkv_t, wo_t, w1_t, w2_t);
  ln_kernel<<<NROWS/4, 256, 0, stream>>>(x, ln1g, ln1b, h_bf);
  gemm_bf16<<<dim3(NROWS/128, 12), 256, 0, stream>>>(h_bf, KP, wqkv_t, KP, qkv, QLD,
      nullptr, nullptr, 0, QLD, KP/32, FLAG_BF16OUT);
  attn_kernel<<<dim3(TSEQ/64, NBATCH*NHEAD), 256, 0, stream>>>(qkv, attn);
  gemm_bf16<<<dim3(NROWS/128, 4), 256, 0, stream>>>(attn, KP, wo_t, KP, x2, EMBED,
      bo, x, EMBED, EMBED, KP/32, 0);
  ln_kernel<<<NROWS/4, 256, 0, stream>>>(x2, ln2g, ln2b, attn /*h2*/);
  gemm_bf16<<<dim3(NROWS/128, 13), 256, 0, stream>>>(attn, KP, w1_t, KP, ff, DFF,
      b1, nullptr, 0, DFF, KP/32, FLAG_BF16OUT | FLAG_RELU);
  gemm_bf16<<<dim3(NROWS/128, 4), 256, 0, stream>>>(ff, DFF, w2_t, DFF, (float*)d_out, EMBED,
      b2, x2, EMBED, EMBED, DFF/32, 0);
}

// Round 3
// 492.055 us; speedup vs baseline: 1.0613x; 1.0613x over previous
//
#include <hip/hip_runtime.h>
#include <stdint.h>

#define TSEQ   2048
#define NBATCH 8
#define NHEAD  4
#define HD     100
#define EMBED  400
#define KP     416      // EMBED padded to multiple of 32
#define QLD    1536     // per-token QKV row: 4 heads * 3 mats * 128 (headdim padded)
#define DFF    1600
#define NROWS  (NBATCH*TSEQ)   // 16384

#define FLAG_RELU    1
#define FLAG_BF16OUT 2

typedef __attribute__((ext_vector_type(4))) float f32x4;
typedef __attribute__((ext_vector_type(8))) short s16x8;
typedef __attribute__((ext_vector_type(4))) unsigned short u16x4;
typedef unsigned short u16;

__device__ __forceinline__ u16 f2bf(float f) {
  union { float f; unsigned u; } v; v.f = f;
  unsigned r = v.u + 0x7FFFu + ((v.u >> 16) & 1u);   // RNE
  return (u16)(r >> 16);
}

__device__ __forceinline__ void gld16(const u16* g, u16* l) {
  __builtin_amdgcn_global_load_lds(
      (const __attribute__((address_space(1))) unsigned*)g,
      (__attribute__((address_space(3))) unsigned*)l, 16, 0, 0);
}

// ---------------- weight repack: fp32 -> bf16, B^T [N][K] layouts ----------
__global__ __launch_bounds__(256) void repack_kernel(
    const float* __restrict__ Wq, const float* __restrict__ Wk, const float* __restrict__ Wv,
    const float* __restrict__ Wo, const float* __restrict__ W1, const float* __restrict__ W2,
    u16* __restrict__ wqkv, u16* __restrict__ wo, u16* __restrict__ w1, u16* __restrict__ w2)
{
  int i = blockIdx.x * 256 + threadIdx.x;
  const int n1 = 1536*KP, n2 = 512*KP, n3 = 1664*KP, n4 = 512*DFF;
  if (i < n1) {            // qkv: n = h*384 + w*128 + d  (w: 0=Q,1=K,2=V)
    int n = i / KP, k = i - n*KP;
    int hh = n / 384, rem = n - hh*384;
    int w = rem >> 7, d = rem & 127;
    float v = 0.f;
    if (k < EMBED && d < HD) {
      const float* W = (w == 0) ? Wq : (w == 1) ? Wk : Wv;
      v = W[(hh*EMBED + k)*HD + d];
    }
    wqkv[i] = f2bf(v);
    return;
  }
  i -= n1;
  if (i < n2) {
    int n = i / KP, k = i - n*KP;
    float v = (n < EMBED && k < EMBED) ? Wo[k*EMBED + n] : 0.f;
    wo[i] = f2bf(v);
    return;
  }
  i -= n2;
  if (i < n3) {
    int n = i / KP, k = i - n*KP;
    float v = (n < DFF && k < EMBED) ? W1[k*DFF + n] : 0.f;
    w1[i] = f2bf(v);
    return;
  }
  i -= n3;
  if (i < n4) {
    int n = i / DFF, k = i - n*DFF;
    float v = (n < EMBED) ? W2[k*EMBED + n] : 0.f;
    w2[i] = f2bf(v);
  }
}

// ---------------- layernorm: fp32 in -> bf16 out [row][KP], pads zeroed ----
__global__ __launch_bounds__(256) void ln_kernel(
    const float* __restrict__ x, const float* __restrict__ gam, const float* __restrict__ bet,
    u16* __restrict__ out)
{
  int wave = threadIdx.x >> 6, lane = threadIdx.x & 63;
  int row = blockIdx.x * 4 + wave;
  const float* xr = x + row*EMBED;
  float v[7]; float s = 0.f;
  #pragma unroll
  for (int j=0;j<7;++j) { int idx = lane + j*64; v[j] = (idx < EMBED) ? xr[idx] : 0.f; s += v[j]; }
  #pragma unroll
  for (int off=1; off<64; off<<=1) s += __shfl_xor(s, off, 64);
  float mu = s * (1.f/EMBED);
  float q = 0.f;
  #pragma unroll
  for (int j=0;j<7;++j) { int idx = lane + j*64; if (idx < EMBED) { float d = v[j]-mu; q += d*d; } }
  #pragma unroll
  for (int off=1; off<64; off<<=1) q += __shfl_xor(q, off, 64);
  float rstd = rsqrtf(q * (1.f/EMBED) + 1e-5f);
  u16* orow = out + row*KP;
  #pragma unroll
  for (int j=0;j<7;++j) {
    int idx = lane + j*64;
    if (idx < KP) {
      float o = (idx < EMBED) ? (v[j]-mu)*rstd*gam[idx] + bet[idx] : 0.f;
      orow[idx] = f2bf(o);
    }
  }
}

// ---------------- generic bf16 GEMM: C = A[M][K] * Bt[N][K]^T + epilogue ----
// 128x128 tile, BK=32, 4 waves (2x2), global_load_lds staging (m97 structure)
__global__ __launch_bounds__(256) void gemm_bf16(
    const u16* __restrict__ A, int lda,
    const u16* __restrict__ Bt, int ldb,
    void* __restrict__ Cout, int ldc,
    const float* __restrict__ bias,
    const float* __restrict__ resid, int ldres,
    int N, int ksteps, int flags)
{
  __shared__ u16 As[128*32];
  __shared__ u16 Bs[128*32];
  const int tid  = threadIdx.x;
  const int lane = tid & 63, wave = tid >> 6;
  const int wm = wave >> 1, wn = wave & 1;
  const int r15 = lane & 15, g = lane >> 4;
  const int brow = blockIdx.x * 128;
  const int bcol = blockIdx.y * 128;

  f32x4 acc[4][4] = {};
  const int c0 = wave*128 + lane;   // this thread's first 16B staging chunk

  for (int ks = 0; ks < ksteps; ++ks) {
    #pragma unroll
    for (int i=0;i<2;++i) {
      int c = c0 + i*64;            // 0..511; wave-contiguous => legal lds dest
      int r = c >> 2, kc = c & 3;
      gld16(A  + (brow + r)*lda + ks*32 + kc*8, As + c*8);
      gld16(Bt + (bcol + r)*ldb + ks*32 + kc*8, Bs + c*8);
    }
    __syncthreads();
    s16x8 af[4], bq[4];
    #pragma unroll
    for (int mi=0;mi<4;++mi)
      af[mi] = *(const s16x8*)(As + (wm*64 + mi*16 + r15)*32 + g*8);
    #pragma unroll
    for (int ni=0;ni<4;++ni)
      bq[ni] = *(const s16x8*)(Bs + (wn*64 + ni*16 + r15)*32 + g*8);
    #pragma unroll
    for (int mi=0;mi<4;++mi)
      #pragma unroll
      for (int ni=0;ni<4;++ni)
        acc[mi][ni] = __builtin_amdgcn_mfma_f32_16x16x32_bf16(af[mi], bq[ni], acc[mi][ni], 0, 0, 0);
    __syncthreads();
  }

  #pragma unroll
  for (int ni=0;ni<4;++ni) {
    const int col = bcol + wn*64 + ni*16 + r15;
    if (col >= N) continue;
    const float bv = bias ? bias[col] : 0.f;
    #pragma unroll
    for (int mi=0;mi<4;++mi) {
      #pragma unroll
      for (int e=0;e<4;++e) {
        const int row = brow + wm*64 + mi*16 + g*4 + e;
        float v = acc[mi][ni][e] + bv;
        if (flags & FLAG_RELU) v = fmaxf(v, 0.f);
        if (resid) v += resid[row*ldres + col];
        if (flags & FLAG_BF16OUT) ((u16*)Cout)[row*ldc + col] = f2bf(v);
        else                      ((float*)Cout)[row*ldc + col] = v;
      }
    }
  }
}

// ---------------- causal flash attention (v2: pipelined) --------------------
// grid (T/128, B*H), 8 waves (512 thr); wave w owns q-rows [w*16, w*16+16).
// Q in regs; K double-buffered via global_load_lds (issued iter-early);
// V reg-staged (T14: load-early / LDS-write-late); exact per-element mask.
#define VS 68   // Vt / Ps padded stride
__global__ __launch_bounds__(512, 4) void attn_kernel(
    const u16* __restrict__ qkv, u16* __restrict__ aout)
{
  const int qt = blockIdx.x;          // 128-row q tile
  const int bh = blockIdx.y;
  const int b = bh >> 2, h = bh & 3;
  const int tid = threadIdx.x;
  const int lane = tid & 63, wave = tid >> 6;
  const int r15 = lane & 15, g = lane >> 4;

  __shared__ u16 Ks[2][64*128];
  __shared__ u16 Vt[112*VS];        // V transposed: [d][kv], single buffer
  __shared__ u16 Ps[8*16*VS];       // per-wave P tile [16][64]

  const int base = (b*TSEQ)*QLD + h*384;
  const int q0 = qt*128;
  const int nt = 2*qt + 2;          // kv tiles

  auto stageK = [&](int buf, int kj) {
    #pragma unroll
    for (int i=0;i<2;++i) {
      int c = (wave*2 + i)*64 + lane;   // 0..1023, wave-contiguous
      int r = c >> 4, pos = c & 15;
      int dc = pos ^ (r & 7);           // pre-swizzled global source
      gld16(qkv + base + 128 + (kj*64 + r)*QLD + dc*8, &Ks[buf][c*8]);
    }
  };

  s16x8 vv[2];
  auto loadV = [&](int kj) {            // issue-early: global -> regs
    #pragma unroll
    for (int i=0;i<2;++i) {
      int c = tid + i*512;
      if (c < 896) {
        int kv = c & 63, dc2 = c >> 6;
        vv[i] = *(const s16x8*)(qkv + base + 256 + (kj*64 + kv)*QLD + dc2*8);
      }
    }
  };
  auto writeV = [&]() {                 // write-late: regs -> LDS transpose
    #pragma unroll
    for (int i=0;i<2;++i) {
      int c = tid + i*512;
      if (c < 896) {
        int kv = c & 63, dc2 = c >> 6;
        #pragma unroll
        for (int e=0;e<8;++e) Vt[(dc2*8+e)*VS + kv] = (u16)vv[i][e];
      }
    }
  };

  // ---- prologue: K0 stage + V0 loads + Q frags, one drain, V0 write ----
  stageK(0, 0);
  loadV(0);
  s16x8 qf[4];
  #pragma unroll
  for (int ks=0;ks<4;++ks)
    qf[ks] = *(const s16x8*)(qkv + base + (q0 + wave*16 + r15)*QLD + ks*32 + g*8);
  __syncthreads();
  writeV();
  __syncthreads();

  f32x4 acc_o[7] = {};
  float m_i[4], l_i[4];
  #pragma unroll
  for (int e=0;e<4;++e){ m_i[e] = -1e30f; l_i[e] = 0.f; }

  for (int kj = 0; kj < nt; ++kj) {
    const int cur = kj & 1;
    if (kj+1 < nt) { stageK(cur^1, kj+1); loadV(kj+1); }   // prefetch in flight

    // wave-level causal skip (must still hit both barriers)
    if (kj*64 <= q0 + wave*16 + 15) {
      // S = Q K^T
      f32x4 sacc[4] = {};
      #pragma unroll
      for (int ni=0;ni<4;++ni) {
        #pragma unroll
        for (int ks=0;ks<4;++ks) {
          int row = ni*16 + r15;
          int pos = (ks*4 + g) ^ (row & 7);
          s16x8 kf = *(const s16x8*)(&Ks[cur][row*128 + pos*8]);
          sacc[ni] = __builtin_amdgcn_mfma_f32_16x16x32_bf16(qf[ks], kf, sacc[ni], 0, 0, 0);
        }
      }

      // scale + exact causal mask + row max (in place in sacc)
      const int qrow_g = q0 + wave*16 + g*4;
      float mx[4];
      #pragma unroll
      for (int e=0;e<4;++e) mx[e] = -1e30f;
      #pragma unroll
      for (int ni=0;ni<4;++ni) {
        int kvg = kj*64 + ni*16 + r15;
        #pragma unroll
        for (int e=0;e<4;++e) {
          float s = sacc[ni][e] * 0.1f;           // 1/sqrt(100)
          if (kvg > qrow_g + e) s = -1e30f;
          sacc[ni][e] = s;
          mx[e] = fmaxf(mx[e], s);
        }
      }
      #pragma unroll
      for (int e=0;e<4;++e) {
        float m = mx[e];
        m = fmaxf(m, __shfl_xor(m, 1, 64));
        m = fmaxf(m, __shfl_xor(m, 2, 64));
        m = fmaxf(m, __shfl_xor(m, 4, 64));
        m = fmaxf(m, __shfl_xor(m, 8, 64));
        mx[e] = m;
      }
      float sc[4];
      #pragma unroll
      for (int e=0;e<4;++e) {
        float mnew = fmaxf(m_i[e], mx[e]);
        sc[e] = __expf(m_i[e] - mnew);
        m_i[e] = mnew;
        float rsum = 0.f;
        #pragma unroll
        for (int ni=0;ni<4;++ni) {
          float pe = __expf(sacc[ni][e] - mnew);
          sacc[ni][e] = pe;
          rsum += pe;
        }
        rsum += __shfl_xor(rsum, 1, 64);
        rsum += __shfl_xor(rsum, 2, 64);
        rsum += __shfl_xor(rsum, 4, 64);
        rsum += __shfl_xor(rsum, 8, 64);
        l_i[e] = l_i[e]*sc[e] + rsum;
      }
      #pragma unroll
      for (int ni=0;ni<7;++ni)
        #pragma unroll
        for (int e=0;e<4;++e) acc_o[ni][e] *= sc[e];

      // P (C-frag) -> LDS -> A-frag (wave-private)
      u16* myP = Ps + wave*16*VS;
      #pragma unroll
      for (int ni=0;ni<4;++ni)
        #pragma unroll
        for (int e=0;e<4;++e)
          myP[(g*4+e)*VS + ni*16 + r15] = f2bf(sacc[ni][e]);
      s16x8 pa[2];
      #pragma unroll
      for (int ks2=0;ks2<2;++ks2)
        pa[ks2] = *(const s16x8*)(myP + r15*VS + ks2*32 + g*8);

      // O += P V
      #pragma unroll
      for (int ni=0;ni<7;++ni) {
        #pragma unroll
        for (int ks2=0;ks2<2;++ks2) {
          s16x8 vf = *(const s16x8*)(Vt + (ni*16 + r15)*VS + ks2*32 + g*8);
          acc_o[ni] = __builtin_amdgcn_mfma_f32_16x16x32_bf16(pa[ks2], vf, acc_o[ni], 0, 0, 0);
        }
      }
    }

    __syncthreads();                      // drains prefetch; protects Ks/Vt
    if (kj+1 < nt) { writeV(); __syncthreads(); }
  }

  // epilogue: out = acc / l, bf16, concat-head layout [row][KP]
  #pragma unroll
  for (int ni=0;ni<7;++ni) {
    int d = ni*16 + r15;
    if (d < HD) {
      #pragma unroll
      for (int e=0;e<4;++e) {
        int row = b*TSEQ + q0 + wave*16 + g*4 + e;
        aout[row*KP + h*HD + d] = f2bf(acc_o[ni][e] / l_i[e]);
      }
    }
  }
  if (h == 0) {  // zero the [400,416) pad columns for the next GEMM
    int r = tid >> 2, c4 = tid & 3;
    int row = b*TSEQ + q0 + r;
    *(u16x4*)(aout + row*KP + EMBED + c4*4) = (u16x4){0,0,0,0};
  }
}

// ---------------------------------------------------------------------------
extern "C" void kernel_launch(void* const* d_in, const int* in_sizes, int n_in,
                              void* d_out, int out_size, void* d_ws, size_t ws_size,
                              hipStream_t stream)
{
  const float* x    = (const float*)d_in[0];
  const float* ln1g = (const float*)d_in[1];
  const float* ln1b = (const float*)d_in[2];
  const float* ln2g = (const float*)d_in[3];
  const float* ln2b = (const float*)d_in[4];
  const float* Wq   = (const float*)d_in[5];
  const float* Wk   = (const float*)d_in[6];
  const float* Wv   = (const float*)d_in[7];
  const float* Wo   = (const float*)d_in[8];
  const float* bo   = (const float*)d_in[9];
  const float* W1   = (const float*)d_in[10];
  const float* b1   = (const float*)d_in[11];
  const float* W2   = (const float*)d_in[12];
  const float* b2   = (const float*)d_in[13];

  u16* wsu = (u16*)d_ws;
  u16* wqkv_t = wsu;                  // [1536][416]
  u16* wo_t   = wsu + 638976;         // [512][416]
  u16* w1_t   = wsu + 851968;         // [1664][416]
  u16* w2_t   = wsu + 1544192;        // [512][1600]
  char* wsb = (char*)d_ws;
  u16* h_bf  = (u16*)(wsb + 4726784);   // [16384][416]
  u16* qkv   = (u16*)(wsb + 18358272);  // [16384][1536]
  u16* attn  = (u16*)(wsb + 68689920);  // [16384][416]; reused as h2 after GEMM2
  u16* ff    = h_bf;                    // [16384][1600]; overlays dead h_bf+qkv
  float* x2  = (float*)d_out;           // x+attn residual lives in d_out

  repack_kernel<<<(2363392 + 255)/256, 256, 0, stream>>>(Wq, Wk, Wv, Wo, W1, W2,
                                                         wqkv_t, wo_t, w1_t, w2_t);
  ln_kernel<<<NROWS/4, 256, 0, stream>>>(x, ln1g, ln1b, h_bf);
  gemm_bf16<<<dim3(NROWS/128, 12), 256, 0, stream>>>(h_bf, KP, wqkv_t, KP, qkv, QLD,
      nullptr, nullptr, 0, QLD, KP/32, FLAG_BF16OUT);
  attn_kernel<<<dim3(TSEQ/128, NBATCH*NHEAD), 512, 0, stream>>>(qkv, attn);
  gemm_bf16<<<dim3(NROWS/128, 4), 256, 0, stream>>>(attn, KP, wo_t, KP, x2, EMBED,
      bo, x, EMBED, EMBED, KP/32, 0);
  ln_kernel<<<NROWS/4, 256, 0, stream>>>(x2, ln2g, ln2b, attn /*h2*/);
  gemm_bf16<<<dim3(NROWS/128, 13), 256, 0, stream>>>(attn, KP, w1_t, KP, ff, DFF,
      b1, nullptr, 0, DFF, KP/32, FLAG_BF16OUT | FLAG_RELU);
  gemm_bf16<<<dim3(NROWS/128, 4), 256, 0, stream>>>(ff, DFF, w2_t, DFF, (float*)d_out, EMBED,
      b2, x2, EMBED, EMBED, DFF/32, 0);
}

// Round 4
// 406.414 us; speedup vs baseline: 1.2849x; 1.2107x over previous
//
#include <hip/hip_runtime.h>
#include <stdint.h>

#define TSEQ   2048
#define NBATCH 8
#define NHEAD  4
#define HD     100
#define EMBED  400
#define KP     416      // EMBED padded to multiple of 32
#define QLD    1536     // per-token QKV row: 4 heads * 3 mats * 128 (headdim padded)
#define DFF    1600
#define NROWS  (NBATCH*TSEQ)   // 16384

#define FLAG_RELU    1
#define FLAG_BF16OUT 2

typedef __attribute__((ext_vector_type(4))) float f32x4;
typedef __attribute__((ext_vector_type(8))) short s16x8;
typedef __attribute__((ext_vector_type(4))) unsigned short u16x4;
typedef unsigned short u16;

__device__ __forceinline__ u16 f2bf(float f) {
  union { float f; unsigned u; } v; v.f = f;
  unsigned r = v.u + 0x7FFFu + ((v.u >> 16) & 1u);   // RNE
  return (u16)(r >> 16);
}

__device__ __forceinline__ void gld16(const u16* g, u16* l) {
  __builtin_amdgcn_global_load_lds(
      (const __attribute__((address_space(1))) unsigned*)g,
      (__attribute__((address_space(3))) unsigned*)l, 16, 0, 0);
}

// ---------------- weight repack: fp32 -> bf16, B^T [N][K] layouts ----------
__global__ __launch_bounds__(256) void repack_kernel(
    const float* __restrict__ Wq, const float* __restrict__ Wk, const float* __restrict__ Wv,
    const float* __restrict__ Wo, const float* __restrict__ W1, const float* __restrict__ W2,
    u16* __restrict__ wqkv, u16* __restrict__ wo, u16* __restrict__ w1, u16* __restrict__ w2)
{
  int i = blockIdx.x * 256 + threadIdx.x;
  const int n1 = 1536*KP, n2 = 512*KP, n3 = 1664*KP, n4 = 512*DFF;
  if (i < n1) {            // qkv: n = h*384 + w*128 + d  (w: 0=Q,1=K,2=V)
    int n = i / KP, k = i - n*KP;
    int hh = n / 384, rem = n - hh*384;
    int w = rem >> 7, d = rem & 127;
    float v = 0.f;
    if (k < EMBED && d < HD) {
      const float* W = (w == 0) ? Wq : (w == 1) ? Wk : Wv;
      v = W[(hh*EMBED + k)*HD + d];
    }
    wqkv[i] = f2bf(v);
    return;
  }
  i -= n1;
  if (i < n2) {
    int n = i / KP, k = i - n*KP;
    float v = (n < EMBED && k < EMBED) ? Wo[k*EMBED + n] : 0.f;
    wo[i] = f2bf(v);
    return;
  }
  i -= n2;
  if (i < n3) {
    int n = i / KP, k = i - n*KP;
    float v = (n < DFF && k < EMBED) ? W1[k*DFF + n] : 0.f;
    w1[i] = f2bf(v);
    return;
  }
  i -= n3;
  if (i < n4) {
    int n = i / DFF, k = i - n*DFF;
    float v = (n < EMBED) ? W2[k*EMBED + n] : 0.f;
    w2[i] = f2bf(v);
  }
}

// ---------------- layernorm: fp32 in -> bf16 out [row][KP], pads zeroed ----
__global__ __launch_bounds__(256) void ln_kernel(
    const float* __restrict__ x, const float* __restrict__ gam, const float* __restrict__ bet,
    u16* __restrict__ out)
{
  int wave = threadIdx.x >> 6, lane = threadIdx.x & 63;
  int row = blockIdx.x * 4 + wave;
  const float* xr = x + row*EMBED;
  float v[7]; float s = 0.f;
  #pragma unroll
  for (int j=0;j<7;++j) { int idx = lane + j*64; v[j] = (idx < EMBED) ? xr[idx] : 0.f; s += v[j]; }
  #pragma unroll
  for (int off=1; off<64; off<<=1) s += __shfl_xor(s, off, 64);
  float mu = s * (1.f/EMBED);
  float q = 0.f;
  #pragma unroll
  for (int j=0;j<7;++j) { int idx = lane + j*64; if (idx < EMBED) { float d = v[j]-mu; q += d*d; } }
  #pragma unroll
  for (int off=1; off<64; off<<=1) q += __shfl_xor(q, off, 64);
  float rstd = rsqrtf(q * (1.f/EMBED) + 1e-5f);
  u16* orow = out + row*KP;
  #pragma unroll
  for (int j=0;j<7;++j) {
    int idx = lane + j*64;
    if (idx < KP) {
      float o = (idx < EMBED) ? (v[j]-mu)*rstd*gam[idx] + bet[idx] : 0.f;
      orow[idx] = f2bf(o);
    }
  }
}

// ---------------- generic bf16 GEMM: C = A[M][K] * Bt[N][K]^T + epilogue ----
// 128x128 tile, BK=32, 4 waves (2x2), global_load_lds staging (m97 structure)
__global__ __launch_bounds__(256) void gemm_bf16(
    const u16* __restrict__ A, int lda,
    const u16* __restrict__ Bt, int ldb,
    void* __restrict__ Cout, int ldc,
    const float* __restrict__ bias,
    const float* __restrict__ resid, int ldres,
    int N, int ksteps, int flags)
{
  __shared__ u16 As[128*32];
  __shared__ u16 Bs[128*32];
  const int tid  = threadIdx.x;
  const int lane = tid & 63, wave = tid >> 6;
  const int wm = wave >> 1, wn = wave & 1;
  const int r15 = lane & 15, g = lane >> 4;
  const int brow = blockIdx.x * 128;
  const int bcol = blockIdx.y * 128;

  f32x4 acc[4][4] = {};
  const int c0 = wave*128 + lane;   // this thread's first 16B staging chunk

  for (int ks = 0; ks < ksteps; ++ks) {
    #pragma unroll
    for (int i=0;i<2;++i) {
      int c = c0 + i*64;            // 0..511; wave-contiguous => legal lds dest
      int r = c >> 2, kc = c & 3;
      gld16(A  + (brow + r)*lda + ks*32 + kc*8, As + c*8);
      gld16(Bt + (bcol + r)*ldb + ks*32 + kc*8, Bs + c*8);
    }
    __syncthreads();
    s16x8 af[4], bq[4];
    #pragma unroll
    for (int mi=0;mi<4;++mi)
      af[mi] = *(const s16x8*)(As + (wm*64 + mi*16 + r15)*32 + g*8);
    #pragma unroll
    for (int ni=0;ni<4;++ni)
      bq[ni] = *(const s16x8*)(Bs + (wn*64 + ni*16 + r15)*32 + g*8);
    #pragma unroll
    for (int mi=0;mi<4;++mi)
      #pragma unroll
      for (int ni=0;ni<4;++ni)
        acc[mi][ni] = __builtin_amdgcn_mfma_f32_16x16x32_bf16(af[mi], bq[ni], acc[mi][ni], 0, 0, 0);
    __syncthreads();
  }

  #pragma unroll
  for (int ni=0;ni<4;++ni) {
    const int col = bcol + wn*64 + ni*16 + r15;
    if (col >= N) continue;
    const float bv = bias ? bias[col] : 0.f;
    #pragma unroll
    for (int mi=0;mi<4;++mi) {
      #pragma unroll
      for (int e=0;e<4;++e) {
        const int row = brow + wm*64 + mi*16 + g*4 + e;
        float v = acc[mi][ni][e] + bv;
        if (flags & FLAG_RELU) v = fmaxf(v, 0.f);
        if (resid) v += resid[row*ldres + col];
        if (flags & FLAG_BF16OUT) ((u16*)Cout)[row*ldc + col] = f2bf(v);
        else                      ((float*)Cout)[row*ldc + col] = v;
      }
    }
  }
}

// ---------------- causal flash attention (v3: paired tiles, no-max softmax) -
// grid (8, B*H). Block p handles q-tiles {p, 15-p} (128 rows each), sharing
// K/V staging -> every block has identical active work (perfect balance).
// Softmax without running max (scores bounded: |S|<<88) -> no cross-lane ops
// in the loop; l reduced once in epilogue.
#define VS 68   // Vt / Ps padded stride
__global__ __launch_bounds__(512, 2) void attn_kernel(
    const u16* __restrict__ qkv, u16* __restrict__ aout)
{
  const int p  = blockIdx.x;          // pair index 0..7
  const int bh = blockIdx.y;
  const int b = bh >> 2, h = bh & 3;
  const int tid = threadIdx.x;
  const int lane = tid & 63, wave = tid >> 6;
  const int r15 = lane & 15, g = lane >> 4;

  __shared__ u16 Ks[2][64*128];
  __shared__ u16 Vt[112*VS];        // V transposed: [d][kv], single buffer
  __shared__ u16 Ps[8*16*VS];       // per-wave P tile [16][64]

  const int base = (b*TSEQ)*QLD + h*384;
  const int q0A = p*128;
  const int q0B = (15-p)*128;
  const int ntB = 2*(15-p) + 2;     // kv tiles for the pair (B dominates)

  auto stageK = [&](int buf, int kj) {
    #pragma unroll
    for (int i=0;i<2;++i) {
      int c = (wave*2 + i)*64 + lane;   // 0..1023, wave-contiguous
      int r = c >> 4, pos = c & 15;
      int dc = pos ^ (r & 7);           // pre-swizzled global source
      gld16(qkv + base + 128 + (kj*64 + r)*QLD + dc*8, &Ks[buf][c*8]);
    }
  };

  s16x8 vv[2];
  auto loadV = [&](int kj) {            // issue-early: global -> regs
    #pragma unroll
    for (int i=0;i<2;++i) {
      int c = tid + i*512;
      if (c < 896) {
        int kv = c & 63, dc2 = c >> 6;
        vv[i] = *(const s16x8*)(qkv + base + 256 + (kj*64 + kv)*QLD + dc2*8);
      }
    }
  };
  auto writeV = [&]() {                 // write-late: regs -> LDS transpose
    #pragma unroll
    for (int i=0;i<2;++i) {
      int c = tid + i*512;
      if (c < 896) {
        int kv = c & 63, dc2 = c >> 6;
        #pragma unroll
        for (int e=0;e<8;++e) Vt[(dc2*8+e)*VS + kv] = (u16)vv[i][e];
      }
    }
  };

  // ---- prologue: K0 stage + V0 loads + Q frags (both tiles) ----
  stageK(0, 0);
  loadV(0);
  s16x8 qfA[4], qfB[4];
  #pragma unroll
  for (int ks=0;ks<4;++ks) {
    qfA[ks] = *(const s16x8*)(qkv + base + (q0A + wave*16 + r15)*QLD + ks*32 + g*8);
    qfB[ks] = *(const s16x8*)(qkv + base + (q0B + wave*16 + r15)*QLD + ks*32 + g*8);
  }
  __syncthreads();
  writeV();
  __syncthreads();

  f32x4 accA[7] = {}, accB[7] = {};
  float lA[4] = {}, lB[4] = {};

  u16* myP = Ps + wave*16*VS;

  auto tileCompute = [&](const s16x8* qf, f32x4* acc, float* lsum, int q0t,
                         int kj, int cur) {
    // S = Q K^T
    f32x4 sacc[4] = {};
    #pragma unroll
    for (int ni=0;ni<4;++ni) {
      #pragma unroll
      for (int ks=0;ks<4;++ks) {
        int row = ni*16 + r15;
        int pos = (ks*4 + g) ^ (row & 7);
        s16x8 kf = *(const s16x8*)(&Ks[cur][row*128 + pos*8]);
        sacc[ni] = __builtin_amdgcn_mfma_f32_16x16x32_bf16(qf[ks], kf, sacc[ni], 0, 0, 0);
      }
    }
    // p = exp(S/10) with exact causal mask; accumulate per-lane l partials
    const int qrow_g = q0t + wave*16 + g*4;
    #pragma unroll
    for (int ni=0;ni<4;++ni) {
      int kvg = kj*64 + ni*16 + r15;
      #pragma unroll
      for (int e=0;e<4;++e) {
        float pe = (kvg > qrow_g + e) ? 0.f : __expf(sacc[ni][e] * 0.1f);
        sacc[ni][e] = pe;
        lsum[e] += pe;
      }
    }
    // P (C-frag) -> LDS -> A-frag (wave-private)
    #pragma unroll
    for (int ni=0;ni<4;++ni)
      #pragma unroll
      for (int e=0;e<4;++e)
        myP[(g*4+e)*VS + ni*16 + r15] = f2bf(sacc[ni][e]);
    s16x8 pa[2];
    #pragma unroll
    for (int ks2=0;ks2<2;++ks2)
      pa[ks2] = *(const s16x8*)(myP + r15*VS + ks2*32 + g*8);
    // O += P V
    #pragma unroll
    for (int ni=0;ni<7;++ni) {
      #pragma unroll
      for (int ks2=0;ks2<2;++ks2) {
        s16x8 vf = *(const s16x8*)(Vt + (ni*16 + r15)*VS + ks2*32 + g*8);
        acc[ni] = __builtin_amdgcn_mfma_f32_16x16x32_bf16(pa[ks2], vf, acc[ni], 0, 0, 0);
      }
    }
  };

  for (int kj = 0; kj < ntB; ++kj) {
    const int cur = kj & 1;
    if (kj+1 < ntB) { stageK(cur^1, kj+1); loadV(kj+1); }   // prefetch in flight
    if (kj*64 <= q0A + wave*16 + 15) tileCompute(qfA, accA, lA, q0A, kj, cur);
    if (kj*64 <= q0B + wave*16 + 15) tileCompute(qfB, accB, lB, q0B, kj, cur);
    __syncthreads();                      // drains prefetch; protects Ks/Vt
    if (kj+1 < ntB) { writeV(); __syncthreads(); }
  }

  // ---- epilogue: reduce l across r15 lanes, divide, store both tiles ----
  #pragma unroll
  for (int e=0;e<4;++e) {
    float a = lA[e], bb = lB[e];
    a += __shfl_xor(a, 1, 64);  bb += __shfl_xor(bb, 1, 64);
    a += __shfl_xor(a, 2, 64);  bb += __shfl_xor(bb, 2, 64);
    a += __shfl_xor(a, 4, 64);  bb += __shfl_xor(bb, 4, 64);
    a += __shfl_xor(a, 8, 64);  bb += __shfl_xor(bb, 8, 64);
    lA[e] = a; lB[e] = bb;
  }
  #pragma unroll
  for (int ni=0;ni<7;++ni) {
    int d = ni*16 + r15;
    if (d < HD) {
      #pragma unroll
      for (int e=0;e<4;++e) {
        int rowA = b*TSEQ + q0A + wave*16 + g*4 + e;
        int rowB = b*TSEQ + q0B + wave*16 + g*4 + e;
        aout[rowA*KP + h*HD + d] = f2bf(accA[ni][e] / lA[e]);
        aout[rowB*KP + h*HD + d] = f2bf(accB[ni][e] / lB[e]);
      }
    }
  }
  if (h == 0) {  // zero the [400,416) pad columns for the next GEMM
    int r = tid >> 2, c4 = tid & 3;
    int rowA = b*TSEQ + q0A + r;
    int rowB = b*TSEQ + q0B + r;
    *(u16x4*)(aout + rowA*KP + EMBED + c4*4) = (u16x4){0,0,0,0};
    *(u16x4*)(aout + rowB*KP + EMBED + c4*4) = (u16x4){0,0,0,0};
  }
}

// ---------------------------------------------------------------------------
extern "C" void kernel_launch(void* const* d_in, const int* in_sizes, int n_in,
                              void* d_out, int out_size, void* d_ws, size_t ws_size,
                              hipStream_t stream)
{
  const float* x    = (const float*)d_in[0];
  const float* ln1g = (const float*)d_in[1];
  const float* ln1b = (const float*)d_in[2];
  const float* ln2g = (const float*)d_in[3];
  const float* ln2b = (const float*)d_in[4];
  const float* Wq   = (const float*)d_in[5];
  const float* Wk   = (const float*)d_in[6];
  const float* Wv   = (const float*)d_in[7];
  const float* Wo   = (const float*)d_in[8];
  const float* bo   = (const float*)d_in[9];
  const float* W1   = (const float*)d_in[10];
  const float* b1   = (const float*)d_in[11];
  const float* W2   = (const float*)d_in[12];
  const float* b2   = (const float*)d_in[13];

  u16* wsu = (u16*)d_ws;
  u16* wqkv_t = wsu;                  // [1536][416]
  u16* wo_t   = wsu + 638976;         // [512][416]
  u16* w1_t   = wsu + 851968;         // [1664][416]
  u16* w2_t   = wsu + 1544192;        // [512][1600]
  char* wsb = (char*)d_ws;
  u16* h_bf  = (u16*)(wsb + 4726784);   // [16384][416]
  u16* qkv   = (u16*)(wsb + 18358272);  // [16384][1536]
  u16* attn  = (u16*)(wsb + 68689920);  // [16384][416]; reused as h2 after GEMM2
  u16* ff    = h_bf;                    // [16384][1600]; overlays dead h_bf+qkv
  float* x2  = (float*)d_out;           // x+attn residual lives in d_out

  repack_kernel<<<(2363392 + 255)/256, 256, 0, stream>>>(Wq, Wk, Wv, Wo, W1, W2,
                                                         wqkv_t, wo_t, w1_t, w2_t);
  ln_kernel<<<NROWS/4, 256, 0, stream>>>(x, ln1g, ln1b, h_bf);
  gemm_bf16<<<dim3(NROWS/128, 12), 256, 0, stream>>>(h_bf, KP, wqkv_t, KP, qkv, QLD,
      nullptr, nullptr, 0, QLD, KP/32, FLAG_BF16OUT);
  attn_kernel<<<dim3(8, NBATCH*NHEAD), 512, 0, stream>>>(qkv, attn);
  gemm_bf16<<<dim3(NROWS/128, 4), 256, 0, stream>>>(attn, KP, wo_t, KP, x2, EMBED,
      bo, x, EMBED, EMBED, KP/32, 0);
  ln_kernel<<<NROWS/4, 256, 0, stream>>>(x2, ln2g, ln2b, attn /*h2*/);
  gemm_bf16<<<dim3(NROWS/128, 13), 256, 0, stream>>>(attn, KP, w1_t, KP, ff, DFF,
      b1, nullptr, 0, DFF, KP/32, FLAG_BF16OUT | FLAG_RELU);
  gemm_bf16<<<dim3(NROWS/128, 4), 256, 0, stream>>>(ff, DFF, w2_t, DFF, (float*)d_out, EMBED,
      b2, x2, EMBED, EMBED, DFF/32, 0);
}

// Round 6
// 394.180 us; speedup vs baseline: 1.3248x; 1.0310x over previous
//
#include <hip/hip_runtime.h>
#include <stdint.h>

#define TSEQ   2048
#define NBATCH 8
#define NHEAD  4
#define HD     100
#define EMBED  400
#define KP     416      // EMBED padded to multiple of 32
#define QLD    1536     // per-token QKV row: 4 heads * 3 mats * 128 (headdim padded)
#define DFF    1600
#define NROWS  (NBATCH*TSEQ)   // 16384

#define FLAG_RELU    1
#define FLAG_BF16OUT 2

typedef __attribute__((ext_vector_type(4))) float f32x4;
typedef __attribute__((ext_vector_type(8))) short s16x8;
typedef __attribute__((ext_vector_type(4))) unsigned short u16x4;
typedef unsigned short u16;

__device__ __forceinline__ u16 f2bf(float f) {
  union { float f; unsigned u; } v; v.f = f;
  unsigned r = v.u + 0x7FFFu + ((v.u >> 16) & 1u);   // RNE
  return (u16)(r >> 16);
}

__device__ __forceinline__ void gld16(const u16* g, u16* l) {
  __builtin_amdgcn_global_load_lds(
      (const __attribute__((address_space(1))) unsigned*)g,
      (__attribute__((address_space(3))) unsigned*)l, 16, 0, 0);
}

// ---------------- weight repack: fp32 -> bf16, B^T [N][K] layouts ----------
// w1_t has 1792 rows (7 x 256 N-tiles), rows >=1600 zeroed.
__global__ __launch_bounds__(256) void repack_kernel(
    const float* __restrict__ Wq, const float* __restrict__ Wk, const float* __restrict__ Wv,
    const float* __restrict__ Wo, const float* __restrict__ W1, const float* __restrict__ W2,
    u16* __restrict__ wqkv, u16* __restrict__ wo, u16* __restrict__ w1, u16* __restrict__ w2)
{
  int i = blockIdx.x * 256 + threadIdx.x;
  const int n1 = 1536*KP, n2 = 512*KP, n3 = 1792*KP, n4 = 512*DFF;
  if (i < n1) {            // qkv: n = h*384 + w*128 + d  (w: 0=Q,1=K,2=V)
    int n = i / KP, k = i - n*KP;
    int hh = n / 384, rem = n - hh*384;
    int w = rem >> 7, d = rem & 127;
    float v = 0.f;
    if (k < EMBED && d < HD) {
      const float* W = (w == 0) ? Wq : (w == 1) ? Wk : Wv;
      v = W[(hh*EMBED + k)*HD + d];
    }
    wqkv[i] = f2bf(v);
    return;
  }
  i -= n1;
  if (i < n2) {
    int n = i / KP, k = i - n*KP;
    float v = (n < EMBED && k < EMBED) ? Wo[k*EMBED + n] : 0.f;
    wo[i] = f2bf(v);
    return;
  }
  i -= n2;
  if (i < n3) {
    int n = i / KP, k = i - n*KP;
    float v = (n < DFF && k < EMBED) ? W1[k*DFF + n] : 0.f;
    w1[i] = f2bf(v);
    return;
  }
  i -= n3;
  if (i < n4) {
    int n = i / DFF, k = i - n*DFF;
    float v = (n < EMBED) ? W2[k*EMBED + n] : 0.f;
    w2[i] = f2bf(v);
  }
}

// ---------------- layernorm: fp32 in -> bf16 out [row][KP], pads zeroed ----
__global__ __launch_bounds__(256) void ln_kernel(
    const float* __restrict__ x, const float* __restrict__ gam, const float* __restrict__ bet,
    u16* __restrict__ out)
{
  int wave = threadIdx.x >> 6, lane = threadIdx.x & 63;
  int row = blockIdx.x * 4 + wave;
  const float* xr = x + row*EMBED;
  float v[7]; float s = 0.f;
  #pragma unroll
  for (int j=0;j<7;++j) { int idx = lane + j*64; v[j] = (idx < EMBED) ? xr[idx] : 0.f; s += v[j]; }
  #pragma unroll
  for (int off=1; off<64; off<<=1) s += __shfl_xor(s, off, 64);
  float mu = s * (1.f/EMBED);
  float q = 0.f;
  #pragma unroll
  for (int j=0;j<7;++j) { int idx = lane + j*64; if (idx < EMBED) { float d = v[j]-mu; q += d*d; } }
  #pragma unroll
  for (int off=1; off<64; off<<=1) q += __shfl_xor(q, off, 64);
  float rstd = rsqrtf(q * (1.f/EMBED) + 1e-5f);
  u16* orow = out + row*KP;
  #pragma unroll
  for (int j=0;j<7;++j) {
    int idx = lane + j*64;
    if (idx < KP) {
      float o = (idx < EMBED) ? (v[j]-mu)*rstd*gam[idx] + bet[idx] : 0.f;
      orow[idx] = f2bf(o);
    }
  }
}

// ---------------- bf16 GEMM v2: 128x256 tile, 8 waves, 2-phase dbuf --------
// C = A[M][K] * Bt[N][K]^T + epilogue. BK=32, KSTEPS compile-time.
// Stage(t+1) issued at top of iter t (prefetch); one barrier per iter.
template<int KSTEPS>
__global__ __launch_bounds__(512, 4) void gemm_bf16(
    const u16* __restrict__ A, int lda,
    const u16* __restrict__ Bt, int ldb,
    void* __restrict__ Cout, int ldc,
    const float* __restrict__ bias,
    const float* __restrict__ resid, int ldres,
    int N, int flags)
{
  __shared__ u16 As[2][128*32];
  __shared__ u16 Bs[2][256*32];
  const int tid  = threadIdx.x;
  const int lane = tid & 63, wave = tid >> 6;
  const int wm = wave >> 2, wn = wave & 3;     // 2 x 4 wave grid
  const int r15 = lane & 15, g = lane >> 4;
  const int brow = blockIdx.x * 128;
  const int bcol = blockIdx.y * 256;

  f32x4 acc[4][4] = {};

  auto stage = [&](int buf, int ks) {
    { int c = tid;               // A: 512 chunks of 16B (128x32 bf16)
      int r = c >> 2, kc = c & 3;
      gld16(A + (brow + r)*lda + ks*32 + kc*8, &As[buf][c*8]); }
    #pragma unroll
    for (int i=0;i<2;++i) {      // B: 1024 chunks (256x32 bf16)
      int c = tid + i*512;
      int r = c >> 2, kc = c & 3;
      gld16(Bt + (bcol + r)*ldb + ks*32 + kc*8, &Bs[buf][c*8]);
    }
  };

  stage(0, 0);
  __syncthreads();                      // vmcnt(0) drain: buf0 ready

  for (int ks = 0; ks < KSTEPS; ++ks) {
    const int cur = ks & 1;
    if (ks+1 < KSTEPS) stage(cur^1, ks+1);    // prefetch in flight
    s16x8 af[4], bq[4];
    #pragma unroll
    for (int mi=0;mi<4;++mi)
      af[mi] = *(const s16x8*)(&As[cur][(wm*64 + mi*16 + r15)*32 + g*8]);
    #pragma unroll
    for (int ni=0;ni<4;++ni)
      bq[ni] = *(const s16x8*)(&Bs[cur][(wn*64 + ni*16 + r15)*32 + g*8]);
    #pragma unroll
    for (int mi=0;mi<4;++mi)
      #pragma unroll
      for (int ni=0;ni<4;++ni)
        acc[mi][ni] = __builtin_amdgcn_mfma_f32_16x16x32_bf16(af[mi], bq[ni], acc[mi][ni], 0, 0, 0);
    __syncthreads();                    // readers done + prefetch complete
  }

  #pragma unroll
  for (int ni=0;ni<4;++ni) {
    const int col = bcol + wn*64 + ni*16 + r15;
    if (col >= N) continue;
    const float bv = bias ? bias[col] : 0.f;
    #pragma unroll
    for (int mi=0;mi<4;++mi) {
      #pragma unroll
      for (int e=0;e<4;++e) {
        const int row = brow + wm*64 + mi*16 + g*4 + e;
        float v = acc[mi][ni][e] + bv;
        if (flags & FLAG_RELU) v = fmaxf(v, 0.f);
        if (resid) v += resid[row*ldres + col];
        if (flags & FLAG_BF16OUT) ((u16*)Cout)[row*ldc + col] = f2bf(v);
        else                      ((float*)Cout)[row*ldc + col] = v;
      }
    }
  }
}

// ---------------- causal flash attention (v3: paired tiles, no-max softmax) -
#define VS 68   // Vt / Ps padded stride
__global__ __launch_bounds__(512, 2) void attn_kernel(
    const u16* __restrict__ qkv, u16* __restrict__ aout)
{
  const int p  = blockIdx.x;          // pair index 0..7
  const int bh = blockIdx.y;
  const int b = bh >> 2, h = bh & 3;
  const int tid = threadIdx.x;
  const int lane = tid & 63, wave = tid >> 6;
  const int r15 = lane & 15, g = lane >> 4;

  __shared__ u16 Ks[2][64*128];
  __shared__ u16 Vt[112*VS];        // V transposed: [d][kv], single buffer
  __shared__ u16 Ps[8*16*VS];       // per-wave P tile [16][64]

  const int base = (b*TSEQ)*QLD + h*384;
  const int q0A = p*128;
  const int q0B = (15-p)*128;
  const int ntB = 2*(15-p) + 2;     // kv tiles for the pair (B dominates)

  auto stageK = [&](int buf, int kj) {
    #pragma unroll
    for (int i=0;i<2;++i) {
      int c = (wave*2 + i)*64 + lane;   // 0..1023, wave-contiguous
      int r = c >> 4, pos = c & 15;
      int dc = pos ^ (r & 7);           // pre-swizzled global source
      gld16(qkv + base + 128 + (kj*64 + r)*QLD + dc*8, &Ks[buf][c*8]);
    }
  };

  s16x8 vv[2];
  auto loadV = [&](int kj) {            // issue-early: global -> regs
    #pragma unroll
    for (int i=0;i<2;++i) {
      int c = tid + i*512;
      if (c < 896) {
        int kv = c & 63, dc2 = c >> 6;
        vv[i] = *(const s16x8*)(qkv + base + 256 + (kj*64 + kv)*QLD + dc2*8);
      }
    }
  };
  auto writeV = [&]() {                 // write-late: regs -> LDS transpose
    #pragma unroll
    for (int i=0;i<2;++i) {
      int c = tid + i*512;
      if (c < 896) {
        int kv = c & 63, dc2 = c >> 6;
        #pragma unroll
        for (int e=0;e<8;++e) Vt[(dc2*8+e)*VS + kv] = (u16)vv[i][e];
      }
    }
  };

  // ---- prologue: K0 stage + V0 loads + Q frags (both tiles) ----
  stageK(0, 0);
  loadV(0);
  s16x8 qfA[4], qfB[4];
  #pragma unroll
  for (int ks=0;ks<4;++ks) {
    qfA[ks] = *(const s16x8*)(qkv + base + (q0A + wave*16 + r15)*QLD + ks*32 + g*8);
    qfB[ks] = *(const s16x8*)(qkv + base + (q0B + wave*16 + r15)*QLD + ks*32 + g*8);
  }
  __syncthreads();
  writeV();
  __syncthreads();

  f32x4 accA[7] = {}, accB[7] = {};
  float lA[4] = {}, lB[4] = {};

  u16* myP = Ps + wave*16*VS;

  auto tileCompute = [&](const s16x8* qf, f32x4* acc, float* lsum, int q0t,
                         int kj, int cur) {
    // S = Q K^T
    f32x4 sacc[4] = {};
    #pragma unroll
    for (int ni=0;ni<4;++ni) {
      #pragma unroll
      for (int ks=0;ks<4;++ks) {
        int row = ni*16 + r15;
        int pos = (ks*4 + g) ^ (row & 7);
        s16x8 kf = *(const s16x8*)(&Ks[cur][row*128 + pos*8]);
        sacc[ni] = __builtin_amdgcn_mfma_f32_16x16x32_bf16(qf[ks], kf, sacc[ni], 0, 0, 0);
      }
    }
    // p = exp(S/10) with exact causal mask; accumulate per-lane l partials
    const int qrow_g = q0t + wave*16 + g*4;
    #pragma unroll
    for (int ni=0;ni<4;++ni) {
      int kvg = kj*64 + ni*16 + r15;
      #pragma unroll
      for (int e=0;e<4;++e) {
        float pe = (kvg > qrow_g + e) ? 0.f : __expf(sacc[ni][e] * 0.1f);
        sacc[ni][e] = pe;
        lsum[e] += pe;
      }
    }
    // P (C-frag) -> LDS -> A-frag (wave-private)
    #pragma unroll
    for (int ni=0;ni<4;++ni)
      #pragma unroll
      for (int e=0;e<4;++e)
        myP[(g*4+e)*VS + ni*16 + r15] = f2bf(sacc[ni][e]);
    s16x8 pa[2];
    #pragma unroll
    for (int ks2=0;ks2<2;++ks2)
      pa[ks2] = *(const s16x8*)(myP + r15*VS + ks2*32 + g*8);
    // O += P V
    #pragma unroll
    for (int ni=0;ni<7;++ni) {
      #pragma unroll
      for (int ks2=0;ks2<2;++ks2) {
        s16x8 vf = *(const s16x8*)(Vt + (ni*16 + r15)*VS + ks2*32 + g*8);
        acc[ni] = __builtin_amdgcn_mfma_f32_16x16x32_bf16(pa[ks2], vf, acc[ni], 0, 0, 0);
      }
    }
  };

  for (int kj = 0; kj < ntB; ++kj) {
    const int cur = kj & 1;
    if (kj+1 < ntB) { stageK(cur^1, kj+1); loadV(kj+1); }   // prefetch in flight
    if (kj*64 <= q0A + wave*16 + 15) tileCompute(qfA, accA, lA, q0A, kj, cur);
    if (kj*64 <= q0B + wave*16 + 15) tileCompute(qfB, accB, lB, q0B, kj, cur);
    __syncthreads();                      // drains prefetch; protects Ks/Vt
    if (kj+1 < ntB) { writeV(); __syncthreads(); }
  }

  // ---- epilogue: reduce l across r15 lanes, divide, store both tiles ----
  #pragma unroll
  for (int e=0;e<4;++e) {
    float a = lA[e], bb = lB[e];
    a += __shfl_xor(a, 1, 64);  bb += __shfl_xor(bb, 1, 64);
    a += __shfl_xor(a, 2, 64);  bb += __shfl_xor(bb, 2, 64);
    a += __shfl_xor(a, 4, 64);  bb += __shfl_xor(bb, 4, 64);
    a += __shfl_xor(a, 8, 64);  bb += __shfl_xor(bb, 8, 64);
    lA[e] = a; lB[e] = bb;
  }
  #pragma unroll
  for (int ni=0;ni<7;++ni) {
    int d = ni*16 + r15;
    if (d < HD) {
      #pragma unroll
      for (int e=0;e<4;++e) {
        int rowA = b*TSEQ + q0A + wave*16 + g*4 + e;
        int rowB = b*TSEQ + q0B + wave*16 + g*4 + e;
        aout[rowA*KP + h*HD + d] = f2bf(accA[ni][e] / lA[e]);
        aout[rowB*KP + h*HD + d] = f2bf(accB[ni][e] / lB[e]);
      }
    }
  }
  if (h == 0) {  // zero the [400,416) pad columns for the next GEMM
    int r = tid >> 2, c4 = tid & 3;
    int rowA = b*TSEQ + q0A + r;
    int rowB = b*TSEQ + q0B + r;
    *(u16x4*)(aout + rowA*KP + EMBED + c4*4) = (u16x4){0,0,0,0};
    *(u16x4*)(aout + rowB*KP + EMBED + c4*4) = (u16x4){0,0,0,0};
  }
}

// ---------------------------------------------------------------------------
extern "C" void kernel_launch(void* const* d_in, const int* in_sizes, int n_in,
                              void* d_out, int out_size, void* d_ws, size_t ws_size,
                              hipStream_t stream)
{
  const float* x    = (const float*)d_in[0];
  const float* ln1g = (const float*)d_in[1];
  const float* ln1b = (const float*)d_in[2];
  const float* ln2g = (const float*)d_in[3];
  const float* ln2b = (const float*)d_in[4];
  const float* Wq   = (const float*)d_in[5];
  const float* Wk   = (const float*)d_in[6];
  const float* Wv   = (const float*)d_in[7];
  const float* Wo   = (const float*)d_in[8];
  const float* bo   = (const float*)d_in[9];
  const float* W1   = (const float*)d_in[10];
  const float* b1   = (const float*)d_in[11];
  const float* W2   = (const float*)d_in[12];
  const float* b2   = (const float*)d_in[13];

  u16* wsu = (u16*)d_ws;
  u16* wqkv_t = wsu;                  // [1536][416]
  u16* wo_t   = wsu + 638976;         // [512][416]
  u16* w1_t   = wsu + 851968;         // [1792][416] (rows >=1600 zero)
  u16* w2_t   = wsu + 1597440;        // [512][1600]
  char* wsb = (char*)d_ws;
  u16* h_bf  = (u16*)(wsb + 4833280);   // [16384][416]
  u16* qkv   = (u16*)(wsb + 18464768);  // [16384][1536]
  u16* attn  = (u16*)(wsb + 68796416);  // [16384][416]; reused as h2 after GEMM2
  u16* ff    = h_bf;                    // [16384][1600]; overlays dead h_bf+qkv
  float* x2  = (float*)d_out;           // x+attn residual lives in d_out

  repack_kernel<<<(2416640 + 255)/256, 256, 0, stream>>>(Wq, Wk, Wv, Wo, W1, W2,
                                                         wqkv_t, wo_t, w1_t, w2_t);
  ln_kernel<<<NROWS/4, 256, 0, stream>>>(x, ln1g, ln1b, h_bf);
  gemm_bf16<13><<<dim3(NROWS/128, 6), 512, 0, stream>>>(h_bf, KP, wqkv_t, KP, qkv, QLD,
      nullptr, nullptr, 0, QLD, FLAG_BF16OUT);
  attn_kernel<<<dim3(8, NBATCH*NHEAD), 512, 0, stream>>>(qkv, attn);
  gemm_bf16<13><<<dim3(NROWS/128, 2), 512, 0, stream>>>(attn, KP, wo_t, KP, x2, EMBED,
      bo, x, EMBED, EMBED, 0);
  ln_kernel<<<NROWS/4, 256, 0, stream>>>(x2, ln2g, ln2b, attn /*h2*/);
  gemm_bf16<13><<<dim3(NROWS/128, 7), 512, 0, stream>>>(attn, KP, w1_t, KP, ff, DFF,
      b1, nullptr, 0, DFF, FLAG_BF16OUT | FLAG_RELU);
  gemm_bf16<50><<<dim3(NROWS/128, 2), 512, 0, stream>>>(ff, DFF, w2_t, DFF, (float*)d_out, EMBED,
      b2, x2, EMBED, EMBED, 0);
}

// Round 10
// 362.718 us; speedup vs baseline: 1.4397x; 1.0867x over previous
//
#include <hip/hip_runtime.h>
#include <stdint.h>

#define TSEQ   2048
#define NBATCH 8
#define NHEAD  4
#define HD     100
#define EMBED  400
#define KP     416      // EMBED padded to multiple of 32
#define QLD    1536     // per-token QKV row: 4 heads * 3 mats * 128 (headdim padded)
#define DFF    1600
#define NROWS  (NBATCH*TSEQ)   // 16384

#define FLAG_RELU    1
#define FLAG_BF16OUT 2

typedef __attribute__((ext_vector_type(4))) float f32x4;
typedef __attribute__((ext_vector_type(8))) short s16x8;
typedef __attribute__((ext_vector_type(4))) unsigned short u16x4;
typedef unsigned short u16;

__device__ __forceinline__ u16 f2bf(float f) {
  union { float f; unsigned u; } v; v.f = f;
  unsigned r = v.u + 0x7FFFu + ((v.u >> 16) & 1u);   // RNE
  return (u16)(r >> 16);
}

__device__ __forceinline__ void gld16(const u16* g, u16* l) {
  __builtin_amdgcn_global_load_lds(
      (const __attribute__((address_space(1))) unsigned*)g,
      (__attribute__((address_space(3))) unsigned*)l, 16, 0, 0);
}

// ---------------- weight repack: fp32 -> bf16, B^T [N][K] layouts ----------
// w1_t has 1792 rows (7 x 256 N-tiles), rows >=1600 zeroed.
__global__ __launch_bounds__(256) void repack_kernel(
    const float* __restrict__ Wq, const float* __restrict__ Wk, const float* __restrict__ Wv,
    const float* __restrict__ Wo, const float* __restrict__ W1, const float* __restrict__ W2,
    u16* __restrict__ wqkv, u16* __restrict__ wo, u16* __restrict__ w1, u16* __restrict__ w2)
{
  int i = blockIdx.x * 256 + threadIdx.x;
  const int n1 = 1536*KP, n2 = 512*KP, n3 = 1792*KP, n4 = 512*DFF;
  if (i < n1) {            // qkv: n = h*384 + w*128 + d  (w: 0=Q,1=K,2=V)
    int n = i / KP, k = i - n*KP;
    int hh = n / 384, rem = n - hh*384;
    int w = rem >> 7, d = rem & 127;
    float v = 0.f;
    if (k < EMBED && d < HD) {
      const float* W = (w == 0) ? Wq : (w == 1) ? Wk : Wv;
      v = W[(hh*EMBED + k)*HD + d];
    }
    wqkv[i] = f2bf(v);
    return;
  }
  i -= n1;
  if (i < n2) {
    int n = i / KP, k = i - n*KP;
    float v = (n < EMBED && k < EMBED) ? Wo[k*EMBED + n] : 0.f;
    wo[i] = f2bf(v);
    return;
  }
  i -= n2;
  if (i < n3) {
    int n = i / KP, k = i - n*KP;
    float v = (n < DFF && k < EMBED) ? W1[k*DFF + n] : 0.f;
    w1[i] = f2bf(v);
    return;
  }
  i -= n3;
  if (i < n4) {
    int n = i / DFF, k = i - n*DFF;
    float v = (n < EMBED) ? W2[k*EMBED + n] : 0.f;
    w2[i] = f2bf(v);
  }
}

// ---------------- layernorm: fp32 in -> bf16 out [row][KP], pads zeroed ----
__global__ __launch_bounds__(256) void ln_kernel(
    const float* __restrict__ x, const float* __restrict__ gam, const float* __restrict__ bet,
    u16* __restrict__ out)
{
  int wave = threadIdx.x >> 6, lane = threadIdx.x & 63;
  int row = blockIdx.x * 4 + wave;
  const float* xr = x + row*EMBED;
  float v[7]; float s = 0.f;
  #pragma unroll
  for (int j=0;j<7;++j) { int idx = lane + j*64; v[j] = (idx < EMBED) ? xr[idx] : 0.f; s += v[j]; }
  #pragma unroll
  for (int off=1; off<64; off<<=1) s += __shfl_xor(s, off, 64);
  float mu = s * (1.f/EMBED);
  float q = 0.f;
  #pragma unroll
  for (int j=0;j<7;++j) { int idx = lane + j*64; if (idx < EMBED) { float d = v[j]-mu; q += d*d; } }
  #pragma unroll
  for (int off=1; off<64; off<<=1) q += __shfl_xor(q, off, 64);
  float rstd = rsqrtf(q * (1.f/EMBED) + 1e-5f);
  u16* orow = out + row*KP;
  #pragma unroll
  for (int j=0;j<7;++j) {
    int idx = lane + j*64;
    if (idx < KP) {
      float o = (idx < EMBED) ? (v[j]-mu)*rstd*gam[idx] + bet[idx] : 0.f;
      orow[idx] = f2bf(o);
    }
  }
}

// ---------------- bf16 GEMM v3: 128x256, 8 waves, 2-phase dbuf, vec epilogue
// C = A[M][K] * Bt[N][K]^T + epilogue. BK=32, KSTEPS compile-time.
// MFMA operands SWAPPED (bq first): each thread's f32x4 spans 4 consecutive
// C-columns at one C-row -> fully vectorized stores/resid/bias.
template<int KSTEPS>
__global__ __launch_bounds__(512, 4) void gemm_bf16(
    const u16* __restrict__ A, int lda,
    const u16* __restrict__ Bt, int ldb,
    void* __restrict__ Cout, int ldc,
    const float* __restrict__ bias,
    const float* __restrict__ resid, int ldres,
    int N, int flags)
{
  __shared__ u16 As[2][128*32];
  __shared__ u16 Bs[2][256*32];
  const int tid  = threadIdx.x;
  const int lane = tid & 63, wave = tid >> 6;
  const int wm = wave >> 2, wn = wave & 3;     // 2 x 4 wave grid
  const int r15 = lane & 15, g = lane >> 4;
  const int brow = blockIdx.x * 128;
  const int bcol = blockIdx.y * 256;

  f32x4 acc[4][4] = {};

  auto stage = [&](int buf, int ks) {
    { int c = tid;               // A: 512 chunks of 16B (128x32 bf16)
      int r = c >> 2, kc = c & 3;
      gld16(A + (brow + r)*lda + ks*32 + kc*8, &As[buf][c*8]); }
    #pragma unroll
    for (int i=0;i<2;++i) {      // B: 1024 chunks (256x32 bf16)
      int c = tid + i*512;
      int r = c >> 2, kc = c & 3;
      gld16(Bt + (bcol + r)*ldb + ks*32 + kc*8, &Bs[buf][c*8]);
    }
  };

  stage(0, 0);
  __syncthreads();                      // vmcnt(0) drain: buf0 ready

  for (int ks = 0; ks < KSTEPS; ++ks) {
    const int cur = ks & 1;
    if (ks+1 < KSTEPS) stage(cur^1, ks+1);    // prefetch in flight
    s16x8 af[4], bq[4];
    #pragma unroll
    for (int mi=0;mi<4;++mi)
      af[mi] = *(const s16x8*)(&As[cur][(wm*64 + mi*16 + r15)*32 + g*8]);
    #pragma unroll
    for (int ni=0;ni<4;++ni)
      bq[ni] = *(const s16x8*)(&Bs[cur][(wn*64 + ni*16 + r15)*32 + g*8]);
    #pragma unroll
    for (int mi=0;mi<4;++mi)
      #pragma unroll
      for (int ni=0;ni<4;++ni)   // swapped: D.col(lane)=C-row, D.rows(regs)=C-cols
        acc[mi][ni] = __builtin_amdgcn_mfma_f32_16x16x32_bf16(bq[ni], af[mi], acc[mi][ni], 0, 0, 0);
    __syncthreads();                    // readers done + prefetch complete
  }

  // vectorized epilogue: per (mi,ni) one f32x4 = 4 consecutive cols at row
  #pragma unroll
  for (int mi=0;mi<4;++mi) {
    const int row = brow + wm*64 + mi*16 + r15;
    #pragma unroll
    for (int ni=0;ni<4;++ni) {
      const int col = bcol + wn*64 + ni*16 + g*4;
      if (col >= N) continue;
      f32x4 v = acc[mi][ni];
      if (bias) v += *(const f32x4*)(bias + col);
      if (flags & FLAG_RELU) {
        #pragma unroll
        for (int e=0;e<4;++e) v[e] = fmaxf(v[e], 0.f);
      }
      if (resid) v += *(const f32x4*)(resid + row*ldres + col);
      if (flags & FLAG_BF16OUT) {
        u16x4 o;
        #pragma unroll
        for (int e=0;e<4;++e) o[e] = f2bf(v[e]);
        *(u16x4*)((u16*)Cout + row*ldc + col) = o;
      } else {
        *(f32x4*)((float*)Cout + row*ldc + col) = v;
      }
    }
  }
}

// ---------------- causal flash attention (v3: paired tiles, no-max softmax) -
#define VS 68   // Vt / Ps padded stride
__global__ __launch_bounds__(512, 2) void attn_kernel(
    const u16* __restrict__ qkv, u16* __restrict__ aout)
{
  const int p  = blockIdx.x;          // pair index 0..7
  const int bh = blockIdx.y;
  const int b = bh >> 2, h = bh & 3;
  const int tid = threadIdx.x;
  const int lane = tid & 63, wave = tid >> 6;
  const int r15 = lane & 15, g = lane >> 4;

  __shared__ u16 Ks[2][64*128];
  __shared__ u16 Vt[112*VS];        // V transposed: [d][kv], single buffer
  __shared__ u16 Ps[8*16*VS];       // per-wave P tile [16][64]

  const int base = (b*TSEQ)*QLD + h*384;
  const int q0A = p*128;
  const int q0B = (15-p)*128;
  const int ntB = 2*(15-p) + 2;     // kv tiles for the pair (B dominates)

  auto stageK = [&](int buf, int kj) {
    #pragma unroll
    for (int i=0;i<2;++i) {
      int c = (wave*2 + i)*64 + lane;   // 0..1023, wave-contiguous
      int r = c >> 4, pos = c & 15;
      int dc = pos ^ (r & 7);           // pre-swizzled global source
      gld16(qkv + base + 128 + (kj*64 + r)*QLD + dc*8, &Ks[buf][c*8]);
    }
  };

  s16x8 vv[2];
  auto loadV = [&](int kj) {            // issue-early: global -> regs
    #pragma unroll
    for (int i=0;i<2;++i) {
      int c = tid + i*512;
      if (c < 896) {
        int kv = c & 63, dc2 = c >> 6;
        vv[i] = *(const s16x8*)(qkv + base + 256 + (kj*64 + kv)*QLD + dc2*8);
      }
    }
  };
  auto writeV = [&]() {                 // write-late: regs -> LDS transpose
    #pragma unroll
    for (int i=0;i<2;++i) {
      int c = tid + i*512;
      if (c < 896) {
        int kv = c & 63, dc2 = c >> 6;
        #pragma unroll
        for (int e=0;e<8;++e) Vt[(dc2*8+e)*VS + kv] = (u16)vv[i][e];
      }
    }
  };

  // ---- prologue: K0 stage + V0 loads + Q frags (both tiles) ----
  stageK(0, 0);
  loadV(0);
  s16x8 qfA[4], qfB[4];
  #pragma unroll
  for (int ks=0;ks<4;++ks) {
    qfA[ks] = *(const s16x8*)(qkv + base + (q0A + wave*16 + r15)*QLD + ks*32 + g*8);
    qfB[ks] = *(const s16x8*)(qkv + base + (q0B + wave*16 + r15)*QLD + ks*32 + g*8);
  }
  __syncthreads();
  writeV();
  __syncthreads();

  f32x4 accA[7] = {}, accB[7] = {};
  float lA[4] = {}, lB[4] = {};

  u16* myP = Ps + wave*16*VS;

  auto tileCompute = [&](const s16x8* qf, f32x4* acc, float* lsum, int q0t,
                         int kj, int cur) {
    // S = Q K^T
    f32x4 sacc[4] = {};
    #pragma unroll
    for (int ni=0;ni<4;++ni) {
      #pragma unroll
      for (int ks=0;ks<4;++ks) {
        int row = ni*16 + r15;
        int pos = (ks*4 + g) ^ (row & 7);
        s16x8 kf = *(const s16x8*)(&Ks[cur][row*128 + pos*8]);
        sacc[ni] = __builtin_amdgcn_mfma_f32_16x16x32_bf16(qf[ks], kf, sacc[ni], 0, 0, 0);
      }
    }
    // p = exp(S/10) with exact causal mask; accumulate per-lane l partials
    const int qrow_g = q0t + wave*16 + g*4;
    #pragma unroll
    for (int ni=0;ni<4;++ni) {
      int kvg = kj*64 + ni*16 + r15;
      #pragma unroll
      for (int e=0;e<4;++e) {
        float pe = (kvg > qrow_g + e) ? 0.f : __expf(sacc[ni][e] * 0.1f);
        sacc[ni][e] = pe;
        lsum[e] += pe;
      }
    }
    // P (C-frag) -> LDS -> A-frag (wave-private)
    #pragma unroll
    for (int ni=0;ni<4;++ni)
      #pragma unroll
      for (int e=0;e<4;++e)
        myP[(g*4+e)*VS + ni*16 + r15] = f2bf(sacc[ni][e]);
    s16x8 pa[2];
    #pragma unroll
    for (int ks2=0;ks2<2;++ks2)
      pa[ks2] = *(const s16x8*)(myP + r15*VS + ks2*32 + g*8);
    // O += P V
    #pragma unroll
    for (int ni=0;ni<7;++ni) {
      #pragma unroll
      for (int ks2=0;ks2<2;++ks2) {
        s16x8 vf = *(const s16x8*)(Vt + (ni*16 + r15)*VS + ks2*32 + g*8);
        acc[ni] = __builtin_amdgcn_mfma_f32_16x16x32_bf16(pa[ks2], vf, acc[ni], 0, 0, 0);
      }
    }
  };

  for (int kj = 0; kj < ntB; ++kj) {
    const int cur = kj & 1;
    if (kj+1 < ntB) { stageK(cur^1, kj+1); loadV(kj+1); }   // prefetch in flight
    if (kj*64 <= q0A + wave*16 + 15) tileCompute(qfA, accA, lA, q0A, kj, cur);
    if (kj*64 <= q0B + wave*16 + 15) tileCompute(qfB, accB, lB, q0B, kj, cur);
    __syncthreads();                      // drains prefetch; protects Ks/Vt
    if (kj+1 < ntB) { writeV(); __syncthreads(); }
  }

  // ---- epilogue: reduce l across r15 lanes, divide, store both tiles ----
  #pragma unroll
  for (int e=0;e<4;++e) {
    float a = lA[e], bb = lB[e];
    a += __shfl_xor(a, 1, 64);  bb += __shfl_xor(bb, 1, 64);
    a += __shfl_xor(a, 2, 64);  bb += __shfl_xor(bb, 2, 64);
    a += __shfl_xor(a, 4, 64);  bb += __shfl_xor(bb, 4, 64);
    a += __shfl_xor(a, 8, 64);  bb += __shfl_xor(bb, 8, 64);
    lA[e] = a; lB[e] = bb;
  }
  #pragma unroll
  for (int ni=0;ni<7;++ni) {
    int d = ni*16 + r15;
    if (d < HD) {
      #pragma unroll
      for (int e=0;e<4;++e) {
        int rowA = b*TSEQ + q0A + wave*16 + g*4 + e;
        int rowB = b*TSEQ + q0B + wave*16 + g*4 + e;
        aout[rowA*KP + h*HD + d] = f2bf(accA[ni][e] / lA[e]);
        aout[rowB*KP + h*HD + d] = f2bf(accB[ni][e] / lB[e]);
      }
    }
  }
  if (h == 0) {  // zero the [400,416) pad columns for the next GEMM
    int r = tid >> 2, c4 = tid & 3;
    int rowA = b*TSEQ + q0A + r;
    int rowB = b*TSEQ + q0B + r;
    *(u16x4*)(aout + rowA*KP + EMBED + c4*4) = (u16x4){0,0,0,0};
    *(u16x4*)(aout + rowB*KP + EMBED + c4*4) = (u16x4){0,0,0,0};
  }
}

// ---------------------------------------------------------------------------
extern "C" void kernel_launch(void* const* d_in, const int* in_sizes, int n_in,
                              void* d_out, int out_size, void* d_ws, size_t ws_size,
                              hipStream_t stream)
{
  const float* x    = (const float*)d_in[0];
  const float* ln1g = (const float*)d_in[1];
  const float* ln1b = (const float*)d_in[2];
  const float* ln2g = (const float*)d_in[3];
  const float* ln2b = (const float*)d_in[4];
  const float* Wq   = (const float*)d_in[5];
  const float* Wk   = (const float*)d_in[6];
  const float* Wv   = (const float*)d_in[7];
  const float* Wo   = (const float*)d_in[8];
  const float* bo   = (const float*)d_in[9];
  const float* W1   = (const float*)d_in[10];
  const float* b1   = (const float*)d_in[11];
  const float* W2   = (const float*)d_in[12];
  const float* b2   = (const float*)d_in[13];

  u16* wsu = (u16*)d_ws;
  u16* wqkv_t = wsu;                  // [1536][416]
  u16* wo_t   = wsu + 638976;         // [512][416]
  u16* w1_t   = wsu + 851968;         // [1792][416] (rows >=1600 zero)
  u16* w2_t   = wsu + 1597440;        // [512][1600]
  char* wsb = (char*)d_ws;
  u16* h_bf  = (u16*)(wsb + 4833280);   // [16384][416]
  u16* qkv   = (u16*)(wsb + 18464768);  // [16384][1536]
  u16* attn  = (u16*)(wsb + 68796416);  // [16384][416]; reused as h2 after GEMM2
  u16* ff    = h_bf;                    // [16384][1600]; overlays dead h_bf+qkv
  float* x2  = (float*)d_out;           // x+attn residual lives in d_out

  repack_kernel<<<(2416640 + 255)/256, 256, 0, stream>>>(Wq, Wk, Wv, Wo, W1, W2,
                                                         wqkv_t, wo_t, w1_t, w2_t);
  ln_kernel<<<NROWS/4, 256, 0, stream>>>(x, ln1g, ln1b, h_bf);
  gemm_bf16<13><<<dim3(NROWS/128, 6), 512, 0, stream>>>(h_bf, KP, wqkv_t, KP, qkv, QLD,
      nullptr, nullptr, 0, QLD, FLAG_BF16OUT);
  attn_kernel<<<dim3(8, NBATCH*NHEAD), 512, 0, stream>>>(qkv, attn);
  gemm_bf16<13><<<dim3(NROWS/128, 2), 512, 0, stream>>>(attn, KP, wo_t, KP, x2, EMBED,
      bo, x, EMBED, EMBED, 0);
  ln_kernel<<<NROWS/4, 256, 0, stream>>>(x2, ln2g, ln2b, attn /*h2*/);
  gemm_bf16<13><<<dim3(NROWS/128, 7), 512, 0, stream>>>(attn, KP, w1_t, KP, ff, DFF,
      b1, nullptr, 0, DFF, FLAG_BF16OUT | FLAG_RELU);
  gemm_bf16<50><<<dim3(NROWS/128, 2), 512, 0, stream>>>(ff, DFF, w2_t, DFF, (float*)d_out, EMBED,
      b2, x2, EMBED, EMBED, 0);
}